// Round 9
// baseline (188.092 us; speedup 1.0000x reference)
//
#include <hip/hip_runtime.h>
#include <hip/hip_bf16.h>
#include <cstddef>

#define CC   128
#define AD   16
#define VD   64
#define HWN  4096
#define PJ   1024
#define NB   8
#define MAGIC 0x13572468u

typedef short short8 __attribute__((ext_vector_type(8)));
typedef float f32x4  __attribute__((ext_vector_type(4)));
typedef unsigned short u16;

__device__ inline u16 f2bf(float f) {
    __hip_bfloat16 h = __float2bfloat16(f);
    union { __hip_bfloat16 h; u16 u; } c; c.h = h; return c.u;
}
__device__ inline unsigned pk2(float a, float b) {
    __hip_bfloat162 h = __float22bfloat162_rn(make_float2(a, b));
    union { __hip_bfloat162 h; unsigned u; } c; c.h = h; return c.u;
}

__device__ inline int ph128(int r, int c) { return r * 128 + ((((c >> 3) ^ (r & 7)) << 3) | (c & 7)); }
__device__ inline int ph64 (int r, int c) { return r * 64  + ((((c >> 3) ^ (r & 7)) << 3) | (c & 7)); }

__device__ inline void stage16(const u16* g, u16* l) {
#if __has_builtin(__builtin_amdgcn_global_load_lds)
    __builtin_amdgcn_global_load_lds(
        (const __attribute__((address_space(1))) unsigned int*)g,
        (__attribute__((address_space(3))) unsigned int*)l, 16, 0, 0);
#else
    *(uint4*)l = *(const uint4*)g;
#endif
}

// ===========================================================================
// FUSED cooperative kernel: proj(+pool) -> per-batch flag barrier -> attn.
// 512 blocks x 256 thr, 56 KB LDS union (2 blocks/CU -> all co-resident).
// Phase bodies are byte-identical to the proven round-8 split kernels.
// Per-batch barrier instead of cg::grid sync (round 7: grid sync = ~48 us).
// ===========================================================================
__global__ __launch_bounds__(256, 2) void k_fused(
    const float* __restrict__ x,
    const float* __restrict__ Wq, const float* __restrict__ bq,
    const float* __restrict__ Wk, const float* __restrict__ bk,
    const float* __restrict__ Wv, const float* __restrict__ bv,
    const float* __restrict__ Wo, const float* __restrict__ bo,
    const float* __restrict__ gma,
    u16* __restrict__ Qp, u16* __restrict__ Kp, u16* __restrict__ Vt,
    unsigned* __restrict__ flags,
    float* __restrict__ out)
{
    __shared__ __align__(16) u16 smem[28672];   // 56 KB union

    const int b = blockIdx.x, t = threadIdx.x;
    const int l = t & 63, w = t >> 6, g = l >> 4, lm = l & 15;
    const int n = b >> 6, m = b & 63;

    // =====================================================================
    // Phase 1: QKV projection + register 2x2 maxpool  (== round-8 k_proj)
    // =====================================================================
    {
        u16* xT = smem;            // [64 pos][128 ch] swizzled (8192 elems)
        u16* WT = smem + 8192;     // [96 n-idx][128 ch] swizzled (12288 elems)

        const int tile = m >> 1, z = m & 1;
        const int p0 = tile * 128;

        {
            const float* xb = x + (size_t)n * CC * HWN + p0 + z * 32;
#pragma unroll
            for (int it = 0; it < 2; ++it) {
                const int idx = t + 256 * it;
                const int p4 = idx & 15, c4 = idx >> 4;
                const int gofs = (p4 & 7) * 4 + (p4 >> 3) * 64;
                const float* bp = xb + gofs;
                const f32x4 r0 = *(const f32x4*)(bp + (size_t)(c4 * 4 + 0) * HWN);
                const f32x4 r1 = *(const f32x4*)(bp + (size_t)(c4 * 4 + 1) * HWN);
                const f32x4 r2 = *(const f32x4*)(bp + (size_t)(c4 * 4 + 2) * HWN);
                const f32x4 r3 = *(const f32x4*)(bp + (size_t)(c4 * 4 + 3) * HWN);
#pragma unroll
                for (int pp = 0; pp < 4; ++pp) {
                    const int lp = p4 * 4 + pp;
                    uint2 v;
                    v.x = pk2(r0[pp], r1[pp]);
                    v.y = pk2(r2[pp], r3[pp]);
                    *(uint2*)&xT[lp * 128 + ((((c4 >> 1) ^ (lp & 7)) << 3) | ((c4 & 1) * 4))] = v;
                }
            }
        }
#pragma unroll
        for (int it = 0; it < 2; ++it) {
            const int idx = t + 256 * it;
            const int d4 = idx & 3, ch = idx >> 2;
            float4 v = *(const float4*)(Wq + ch * AD + d4 * 4);
            WT[ph128(d4 * 4 + 0, ch)] = f2bf(v.x);
            WT[ph128(d4 * 4 + 1, ch)] = f2bf(v.y);
            WT[ph128(d4 * 4 + 2, ch)] = f2bf(v.z);
            WT[ph128(d4 * 4 + 3, ch)] = f2bf(v.w);
            v = *(const float4*)(Wk + ch * AD + d4 * 4);
            WT[ph128(16 + d4 * 4 + 0, ch)] = f2bf(v.x);
            WT[ph128(16 + d4 * 4 + 1, ch)] = f2bf(v.y);
            WT[ph128(16 + d4 * 4 + 2, ch)] = f2bf(v.z);
            WT[ph128(16 + d4 * 4 + 3, ch)] = f2bf(v.w);
        }
#pragma unroll
        for (int it = 0; it < 8; ++it) {
            const int idx = t + 256 * it;
            const int d4 = idx & 15, ch = idx >> 4;
            const float4 v = *(const float4*)(Wv + ch * VD + d4 * 4);
            WT[ph128(32 + d4 * 4 + 0, ch)] = f2bf(v.x);
            WT[ph128(32 + d4 * 4 + 1, ch)] = f2bf(v.y);
            WT[ph128(32 + d4 * 4 + 2, ch)] = f2bf(v.z);
            WT[ph128(32 + d4 * 4 + 3, ch)] = f2bf(v.w);
        }
        __syncthreads();

        const int pw = w & 1, ng = w >> 1;
        f32x4 acc[2][3];
#pragma unroll
        for (int i = 0; i < 2; ++i)
#pragma unroll
            for (int j = 0; j < 3; ++j) acc[i][j] = (f32x4){0.f, 0.f, 0.f, 0.f};
#pragma unroll
        for (int ks = 0; ks < 4; ++ks) {
            const short8 a0 = *(const short8*)&xT[ph128(pw * 16 + lm,      ks * 32 + g * 8)];
            const short8 a1 = *(const short8*)&xT[ph128(32 + pw * 16 + lm, ks * 32 + g * 8)];
#pragma unroll
            for (int j = 0; j < 3; ++j) {
                const short8 bb = *(const short8*)&WT[ph128((ng * 3 + j) * 16 + lm, ks * 32 + g * 8)];
                acc[0][j] = __builtin_amdgcn_mfma_f32_16x16x32_bf16(a0, bb, acc[0][j], 0, 0, 0);
                acc[1][j] = __builtin_amdgcn_mfma_f32_16x16x32_bf16(a1, bb, acc[1][j], 0, 0, 0);
            }
        }

        const int pbase = p0 + z * 32 + pw * 16 + g * 4;
        const int jp = tile * 32 + z * 16 + pw * 8 + g * 2;

        if (ng == 0) {
            const float bqv = bq[lm];
#pragma unroll
            for (int mi = 0; mi < 2; ++mi)
#pragma unroll
                for (int r = 0; r < 4; ++r)
                    Qp[((size_t)n * HWN + pbase + mi * 64 + r) * AD + lm] = f2bf(acc[mi][0][r] + bqv);
            const float bkv = bk[lm];
#pragma unroll
            for (int a = 0; a < 2; ++a) {
                const float mx = fmaxf(fmaxf(acc[0][1][2 * a], acc[0][1][2 * a + 1]),
                                       fmaxf(acc[1][1][2 * a], acc[1][1][2 * a + 1])) + bkv;
                Kp[((size_t)n * PJ + jp + a) * AD + lm] = f2bf(mx);
            }
            {
                const float bvv = bv[lm];
                const float m0 = fmaxf(fmaxf(acc[0][2][0], acc[0][2][1]),
                                       fmaxf(acc[1][2][0], acc[1][2][1])) + bvv;
                const float m1 = fmaxf(fmaxf(acc[0][2][2], acc[0][2][3]),
                                       fmaxf(acc[1][2][2], acc[1][2][3])) + bvv;
                *(unsigned*)&Vt[((size_t)n * VD + lm) * PJ + jp] = pk2(m0, m1);
            }
        } else {
#pragma unroll
            for (int j = 0; j < 3; ++j) {
                const int dv = (j + 1) * 16 + lm;
                const float bvv = bv[dv];
                const float m0 = fmaxf(fmaxf(acc[0][j][0], acc[0][j][1]),
                                       fmaxf(acc[1][j][0], acc[1][j][1])) + bvv;
                const float m1 = fmaxf(fmaxf(acc[0][j][2], acc[0][j][3]),
                                       fmaxf(acc[1][j][2], acc[1][j][3])) + bvv;
                *(unsigned*)&Vt[((size_t)n * VD + dv) * PJ + jp] = pk2(m0, m1);
            }
        }
    }

    // =====================================================================
    // Per-batch flag barrier: 64 producers of batch n signal; this block
    // waits for all 64 of its own batch.  Magic-valued flags are robust to
    // the 0xAA ws poison (and to stale-MAGIC replays: prior launch wrote
    // identical ws values).
    // =====================================================================
    __syncthreads();                       // all proj stores drained (vmcnt0)
    if (t == 0) {
        __threadfence();                   // agent fence: L2 writeback
        __hip_atomic_store(&flags[n * 64 + m], MAGIC,
                           __ATOMIC_RELAXED, __HIP_MEMORY_SCOPE_AGENT);
    }
    if (t < 64) {
        while (__hip_atomic_load(&flags[n * 64 + t],
                                 __ATOMIC_RELAXED, __HIP_MEMORY_SCOPE_AGENT) != MAGIC)
            __builtin_amdgcn_s_sleep(2);
    }
    __syncthreads();
    __threadfence();                       // acquire: invalidate stale cache

    // =====================================================================
    // Phase 2: flash attention + out-proj + residual  (== round-8 k_attn)
    // =====================================================================
    {
        u16* PB = smem + 20480;            // per-wave P; reused as O^T
        u16* Pl = PB + w * 2048;

        const int q0b = m * 64;

        short8 qf = {0, 0, 0, 0, 0, 0, 0, 0};
        if (g < 2)
            qf = *(const short8*)(Qp + ((size_t)n * HWN + q0b + w * 16 + lm) * AD + g * 8);

        const u16* Kg = Kp + (size_t)n * PJ * AD
                      + (size_t)(t >> 1) * AD + ((t & 1) ^ ((t >> 1) & 1)) * 8;
        const u16* Vg0 = Vt + (size_t)n * VD * PJ;

        f32x4 O[4];
#pragma unroll
        for (int i = 0; i < 4; ++i) O[i] = (f32x4){0.f, 0.f, 0.f, 0.f};
        float mr = -1e30f, lr = 0.f;       // per q = lm (replicated across g)

        for (int pair = 0; pair < 4; ++pair) {
#pragma unroll
            for (int s = 0; s < 2; ++s) {
                u16* Kb = smem + s * 10240;
                const int j0 = (pair * 2 + s) * 128;
                stage16(Kg + (size_t)j0 * AD, &Kb[t * 8]);
#pragma unroll
                for (int i = 0; i < 4; ++i) {
                    const int dv = w * 16 + i * 4 + g;
                    stage16(Vg0 + (size_t)dv * PJ + j0 + (((l & 15) ^ (dv & 7)) * 8),
                            &Kb[2048 + (w * 4 + i) * 512 + l * 8]);
                }
            }
            __syncthreads();

#pragma unroll
            for (int s = 0; s < 2; ++s) {
                const u16* Kl = smem + s * 10240;
                const u16* Vl = Kl + 2048;

                // scores^T: St[row=j-in-tile=4g+r][col=q=lm]
                f32x4 St[8];
#pragma unroll
                for (int jt = 0; jt < 8; ++jt) {
                    short8 kb = {0, 0, 0, 0, 0, 0, 0, 0};
                    if (g < 2) {
                        const int j = jt * 16 + lm;
                        kb = *(const short8*)&Kl[(j * 2 + (g ^ (j & 1))) * 8];
                    }
                    const f32x4 z4 = (f32x4){0.f, 0.f, 0.f, 0.f};
                    St[jt] = __builtin_amdgcn_mfma_f32_16x16x32_bf16(kb, qf, z4, 0, 0, 0);
                }

                // online softmax: register tree + 2 shfl_xor
                float cm = St[0][0];
#pragma unroll
                for (int jt = 0; jt < 8; ++jt)
#pragma unroll
                    for (int r = 0; r < 4; ++r) cm = fmaxf(cm, St[jt][r]);
                cm = fmaxf(cm, __shfl_xor(cm, 16));
                cm = fmaxf(cm, __shfl_xor(cm, 32));
                const float nm = fmaxf(mr, cm);
                const float al = __expf(mr - nm);
                mr = nm;
                float sum = 0.f;
#pragma unroll
                for (int jt = 0; jt < 8; ++jt)
#pragma unroll
                    for (int r = 0; r < 4; ++r) {
                        const float p = __expf(St[jt][r] - nm);
                        St[jt][r] = p;
                        sum += p;
                    }
                sum += __shfl_xor(sum, 16);
                sum += __shfl_xor(sum, 32);
                lr = lr * al + sum;

#pragma unroll
                for (int r = 0; r < 4; ++r) {
                    const float ar = __shfl(al, g * 4 + r);
                    O[0][r] *= ar; O[1][r] *= ar; O[2][r] *= ar; O[3][r] *= ar;
                }

#pragma unroll
                for (int jt = 0; jt < 8; ++jt) {
                    uint2 dw;
                    dw.x = pk2(St[jt][0], St[jt][1]);
                    dw.y = pk2(St[jt][2], St[jt][3]);
                    *(uint2*)&Pl[lm * 128 + (((2 * jt + (g >> 1)) ^ (lm & 7)) << 3) + 4 * (g & 1)] = dw;
                }

#pragma unroll
                for (int ks = 0; ks < 4; ++ks) {
                    const short8 pf = *(const short8*)&Pl[ph128(lm, ks * 32 + g * 8)];
#pragma unroll
                    for (int dt = 0; dt < 4; ++dt) {
                        const short8 vf = *(const short8*)&Vl[ph128(dt * 16 + lm, ks * 32 + g * 8)];
                        O[dt] = __builtin_amdgcn_mfma_f32_16x16x32_bf16(pf, vf, O[dt], 0, 0, 0);
                    }
                }
            }
            __syncthreads();
        }

        // normalize, O^T -> per-wave LDS
        const float invq = 1.f / lr;
        u16* Ol = Pl;
#pragma unroll
        for (int r = 0; r < 4; ++r) {
            const float inv = __shfl(invq, g * 4 + r);
            const int row = g * 4 + r;
#pragma unroll
            for (int dt = 0; dt < 4; ++dt)
                Ol[ph64(row, dt * 16 + lm)] = f2bf(O[dt][r] * inv);
        }
        // stage WoT[c][dv] into KV region (dead)
        u16* WoTl = smem;
#pragma unroll
        for (int it = 0; it < 8; ++it) {
            const int idx = t + 256 * it;
            const int c4 = idx & 31, dv = idx >> 5;
            const float4 v = *(const float4*)(Wo + dv * CC + c4 * 4);
            WoTl[ph64(c4 * 4 + 0, dv)] = f2bf(v.x);
            WoTl[ph64(c4 * 4 + 1, dv)] = f2bf(v.y);
            WoTl[ph64(c4 * 4 + 2, dv)] = f2bf(v.z);
            WoTl[ph64(c4 * 4 + 3, dv)] = f2bf(v.w);
        }
        __syncthreads();

        const float gm = gma[0];
#pragma unroll
        for (int mt = 0; mt < 8; ++mt) {
            float xr[4];
            const size_t obase = ((size_t)n * CC + mt * 16 + g * 4) * HWN + q0b + w * 16 + lm;
#pragma unroll
            for (int r = 0; r < 4; ++r) xr[r] = x[obase + (size_t)r * HWN];
            f32x4 D = (f32x4){0.f, 0.f, 0.f, 0.f};
#pragma unroll
            for (int ks = 0; ks < 2; ++ks) {
                const short8 af = *(const short8*)&WoTl[ph64(mt * 16 + lm, ks * 32 + g * 8)];
                const short8 bf = *(const short8*)&Ol[ph64(lm, ks * 32 + g * 8)];
                D = __builtin_amdgcn_mfma_f32_16x16x32_bf16(af, bf, D, 0, 0, 0);
            }
#pragma unroll
            for (int r = 0; r < 4; ++r) {
                const int c = mt * 16 + g * 4 + r;
                out[obase + (size_t)r * HWN] = xr[r] + gm * (D[r] + bo[c]);
            }
        }
    }
}

// ===========================================================================
// FALLBACK split kernels (round 8, proven) — used only if coop launch fails.
// ===========================================================================
__global__ __launch_bounds__(256, 4) void k_proj(
    const float* __restrict__ x,
    const float* __restrict__ Wq, const float* __restrict__ bq,
    const float* __restrict__ Wk, const float* __restrict__ bk,
    const float* __restrict__ Wv, const float* __restrict__ bv,
    u16* __restrict__ Qp, u16* __restrict__ Kp, u16* __restrict__ Vt)
{
    __shared__ __align__(16) u16 xT[64 * 128];
    __shared__ __align__(16) u16 WT[96 * 128];

    const int tile = blockIdx.x, n = blockIdx.y, z = blockIdx.z, t = threadIdx.x;
    const int l = t & 63, w = t >> 6, g = l >> 4, lm = l & 15;
    const int p0 = tile * 128;

    {
        const float* xb = x + (size_t)n * CC * HWN + p0 + z * 32;
#pragma unroll
        for (int it = 0; it < 2; ++it) {
            const int idx = t + 256 * it;
            const int p4 = idx & 15, c4 = idx >> 4;
            const int gofs = (p4 & 7) * 4 + (p4 >> 3) * 64;
            const float* bp = xb + gofs;
            const f32x4 r0 = *(const f32x4*)(bp + (size_t)(c4 * 4 + 0) * HWN);
            const f32x4 r1 = *(const f32x4*)(bp + (size_t)(c4 * 4 + 1) * HWN);
            const f32x4 r2 = *(const f32x4*)(bp + (size_t)(c4 * 4 + 2) * HWN);
            const f32x4 r3 = *(const f32x4*)(bp + (size_t)(c4 * 4 + 3) * HWN);
#pragma unroll
            for (int pp = 0; pp < 4; ++pp) {
                const int lp = p4 * 4 + pp;
                uint2 v;
                v.x = pk2(r0[pp], r1[pp]);
                v.y = pk2(r2[pp], r3[pp]);
                *(uint2*)&xT[lp * 128 + ((((c4 >> 1) ^ (lp & 7)) << 3) | ((c4 & 1) * 4))] = v;
            }
        }
    }
#pragma unroll
    for (int it = 0; it < 2; ++it) {
        const int idx = t + 256 * it;
        const int d4 = idx & 3, ch = idx >> 2;
        float4 v = *(const float4*)(Wq + ch * AD + d4 * 4);
        WT[ph128(d4 * 4 + 0, ch)] = f2bf(v.x);
        WT[ph128(d4 * 4 + 1, ch)] = f2bf(v.y);
        WT[ph128(d4 * 4 + 2, ch)] = f2bf(v.z);
        WT[ph128(d4 * 4 + 3, ch)] = f2bf(v.w);
        v = *(const float4*)(Wk + ch * AD + d4 * 4);
        WT[ph128(16 + d4 * 4 + 0, ch)] = f2bf(v.x);
        WT[ph128(16 + d4 * 4 + 1, ch)] = f2bf(v.y);
        WT[ph128(16 + d4 * 4 + 2, ch)] = f2bf(v.z);
        WT[ph128(16 + d4 * 4 + 3, ch)] = f2bf(v.w);
    }
#pragma unroll
    for (int it = 0; it < 8; ++it) {
        const int idx = t + 256 * it;
        const int d4 = idx & 15, ch = idx >> 4;
        const float4 v = *(const float4*)(Wv + ch * VD + d4 * 4);
        WT[ph128(32 + d4 * 4 + 0, ch)] = f2bf(v.x);
        WT[ph128(32 + d4 * 4 + 1, ch)] = f2bf(v.y);
        WT[ph128(32 + d4 * 4 + 2, ch)] = f2bf(v.z);
        WT[ph128(32 + d4 * 4 + 3, ch)] = f2bf(v.w);
    }
    __syncthreads();

    const int pw = w & 1, ng = w >> 1;
    f32x4 acc[2][3];
#pragma unroll
    for (int i = 0; i < 2; ++i)
#pragma unroll
        for (int j = 0; j < 3; ++j) acc[i][j] = (f32x4){0.f, 0.f, 0.f, 0.f};
#pragma unroll
    for (int ks = 0; ks < 4; ++ks) {
        const short8 a0 = *(const short8*)&xT[ph128(pw * 16 + lm,      ks * 32 + g * 8)];
        const short8 a1 = *(const short8*)&xT[ph128(32 + pw * 16 + lm, ks * 32 + g * 8)];
#pragma unroll
        for (int j = 0; j < 3; ++j) {
            const short8 b = *(const short8*)&WT[ph128((ng * 3 + j) * 16 + lm, ks * 32 + g * 8)];
            acc[0][j] = __builtin_amdgcn_mfma_f32_16x16x32_bf16(a0, b, acc[0][j], 0, 0, 0);
            acc[1][j] = __builtin_amdgcn_mfma_f32_16x16x32_bf16(a1, b, acc[1][j], 0, 0, 0);
        }
    }

    const int pbase = p0 + z * 32 + pw * 16 + g * 4;
    const int jp = tile * 32 + z * 16 + pw * 8 + g * 2;

    if (ng == 0) {
        const float bqv = bq[lm];
#pragma unroll
        for (int mi = 0; mi < 2; ++mi)
#pragma unroll
            for (int r = 0; r < 4; ++r)
                Qp[((size_t)n * HWN + pbase + mi * 64 + r) * AD + lm] = f2bf(acc[mi][0][r] + bqv);
        const float bkv = bk[lm];
#pragma unroll
        for (int a = 0; a < 2; ++a) {
            const float mx = fmaxf(fmaxf(acc[0][1][2 * a], acc[0][1][2 * a + 1]),
                                   fmaxf(acc[1][1][2 * a], acc[1][1][2 * a + 1])) + bkv;
            Kp[((size_t)n * PJ + jp + a) * AD + lm] = f2bf(mx);
        }
        {
            const float bvv = bv[lm];
            const float m0 = fmaxf(fmaxf(acc[0][2][0], acc[0][2][1]),
                                   fmaxf(acc[1][2][0], acc[1][2][1])) + bvv;
            const float m1 = fmaxf(fmaxf(acc[0][2][2], acc[0][2][3]),
                                   fmaxf(acc[1][2][2], acc[1][2][3])) + bvv;
            *(unsigned*)&Vt[((size_t)n * VD + lm) * PJ + jp] = pk2(m0, m1);
        }
    } else {
#pragma unroll
        for (int j = 0; j < 3; ++j) {
            const int dv = (j + 1) * 16 + lm;
            const float bvv = bv[dv];
            const float m0 = fmaxf(fmaxf(acc[0][j][0], acc[0][j][1]),
                                   fmaxf(acc[1][j][0], acc[1][j][1])) + bvv;
            const float m1 = fmaxf(fmaxf(acc[0][j][2], acc[0][j][3]),
                                   fmaxf(acc[1][j][2], acc[1][j][3])) + bvv;
            *(unsigned*)&Vt[((size_t)n * VD + dv) * PJ + jp] = pk2(m0, m1);
        }
    }
}

__global__ __launch_bounds__(256, 4) void k_attn(
    const float* __restrict__ x,
    const u16* __restrict__ Qp, const u16* __restrict__ Kp, const u16* __restrict__ Vt,
    const float* __restrict__ Wo, const float* __restrict__ bo,
    const float* __restrict__ gma,
    float* __restrict__ out)
{
    __shared__ __align__(16) u16 KV[2][10240];
    __shared__ __align__(16) u16 PB[4 * 2048];

    const int n = blockIdx.y, t = threadIdx.x;
    const int q0b = blockIdx.x * 64;
    const int l = t & 63, w = t >> 6, g = l >> 4, lm = l & 15;

    short8 qf = {0, 0, 0, 0, 0, 0, 0, 0};
    if (g < 2)
        qf = *(const short8*)(Qp + ((size_t)n * HWN + q0b + w * 16 + lm) * AD + g * 8);

    const u16* Kg = Kp + (size_t)n * PJ * AD
                  + (size_t)(t >> 1) * AD + ((t & 1) ^ ((t >> 1) & 1)) * 8;
    const u16* Vg0 = Vt + (size_t)n * VD * PJ;

    u16* Pl = PB + w * 2048;

    f32x4 O[4];
#pragma unroll
    for (int i = 0; i < 4; ++i) O[i] = (f32x4){0.f, 0.f, 0.f, 0.f};
    float mr = -1e30f, lr = 0.f;

    for (int pair = 0; pair < 4; ++pair) {
#pragma unroll
        for (int s = 0; s < 2; ++s) {
            const int j0 = (pair * 2 + s) * 128;
            stage16(Kg + (size_t)j0 * AD, &KV[s][t * 8]);
#pragma unroll
            for (int i = 0; i < 4; ++i) {
                const int dv = w * 16 + i * 4 + g;
                stage16(Vg0 + (size_t)dv * PJ + j0 + (((l & 15) ^ (dv & 7)) * 8),
                        &KV[s][2048 + (w * 4 + i) * 512 + l * 8]);
            }
        }
        __syncthreads();

#pragma unroll
        for (int s = 0; s < 2; ++s) {
            const u16* Kl = KV[s];
            const u16* Vl = KV[s] + 2048;

            f32x4 St[8];
#pragma unroll
            for (int jt = 0; jt < 8; ++jt) {
                short8 kb = {0, 0, 0, 0, 0, 0, 0, 0};
                if (g < 2) {
                    const int j = jt * 16 + lm;
                    kb = *(const short8*)&Kl[(j * 2 + (g ^ (j & 1))) * 8];
                }
                const f32x4 z4 = (f32x4){0.f, 0.f, 0.f, 0.f};
                St[jt] = __builtin_amdgcn_mfma_f32_16x16x32_bf16(kb, qf, z4, 0, 0, 0);
            }

            float cm = St[0][0];
#pragma unroll
            for (int jt = 0; jt < 8; ++jt)
#pragma unroll
                for (int r = 0; r < 4; ++r) cm = fmaxf(cm, St[jt][r]);
            cm = fmaxf(cm, __shfl_xor(cm, 16));
            cm = fmaxf(cm, __shfl_xor(cm, 32));
            const float nm = fmaxf(mr, cm);
            const float al = __expf(mr - nm);
            mr = nm;
            float sum = 0.f;
#pragma unroll
            for (int jt = 0; jt < 8; ++jt)
#pragma unroll
                for (int r = 0; r < 4; ++r) {
                    const float p = __expf(St[jt][r] - nm);
                    St[jt][r] = p;
                    sum += p;
                }
            sum += __shfl_xor(sum, 16);
            sum += __shfl_xor(sum, 32);
            lr = lr * al + sum;

#pragma unroll
            for (int r = 0; r < 4; ++r) {
                const float ar = __shfl(al, g * 4 + r);
                O[0][r] *= ar; O[1][r] *= ar; O[2][r] *= ar; O[3][r] *= ar;
            }

#pragma unroll
            for (int jt = 0; jt < 8; ++jt) {
                uint2 dw;
                dw.x = pk2(St[jt][0], St[jt][1]);
                dw.y = pk2(St[jt][2], St[jt][3]);
                *(uint2*)&Pl[lm * 128 + (((2 * jt + (g >> 1)) ^ (lm & 7)) << 3) + 4 * (g & 1)] = dw;
            }

#pragma unroll
            for (int ks = 0; ks < 4; ++ks) {
                const short8 pf = *(const short8*)&Pl[ph128(lm, ks * 32 + g * 8)];
#pragma unroll
                for (int dt = 0; dt < 4; ++dt) {
                    const short8 vf = *(const short8*)&Vl[ph128(dt * 16 + lm, ks * 32 + g * 8)];
                    O[dt] = __builtin_amdgcn_mfma_f32_16x16x32_bf16(pf, vf, O[dt], 0, 0, 0);
                }
            }
        }
        __syncthreads();
    }

    const float invq = 1.f / lr;
    u16* Ol = Pl;
#pragma unroll
    for (int r = 0; r < 4; ++r) {
        const float inv = __shfl(invq, g * 4 + r);
        const int row = g * 4 + r;
#pragma unroll
        for (int dt = 0; dt < 4; ++dt)
            Ol[ph64(row, dt * 16 + lm)] = f2bf(O[dt][r] * inv);
    }
    u16* WoTl = (u16*)KV;
#pragma unroll
    for (int it = 0; it < 8; ++it) {
        const int idx = t + 256 * it;
        const int c4 = idx & 31, dv = idx >> 5;
        const float4 v = *(const float4*)(Wo + dv * CC + c4 * 4);
        WoTl[ph64(c4 * 4 + 0, dv)] = f2bf(v.x);
        WoTl[ph64(c4 * 4 + 1, dv)] = f2bf(v.y);
        WoTl[ph64(c4 * 4 + 2, dv)] = f2bf(v.z);
        WoTl[ph64(c4 * 4 + 3, dv)] = f2bf(v.w);
    }
    __syncthreads();

    const float gm = gma[0];
#pragma unroll
    for (int mt = 0; mt < 8; ++mt) {
        float xr[4];
        const size_t obase = ((size_t)n * CC + mt * 16 + g * 4) * HWN + q0b + w * 16 + lm;
#pragma unroll
        for (int r = 0; r < 4; ++r) xr[r] = x[obase + (size_t)r * HWN];
        f32x4 D = (f32x4){0.f, 0.f, 0.f, 0.f};
#pragma unroll
        for (int ks = 0; ks < 2; ++ks) {
            const short8 af = *(const short8*)&WoTl[ph64(mt * 16 + lm, ks * 32 + g * 8)];
            const short8 bf = *(const short8*)&Ol[ph64(lm, ks * 32 + g * 8)];
            D = __builtin_amdgcn_mfma_f32_16x16x32_bf16(af, bf, D, 0, 0, 0);
        }
#pragma unroll
        for (int r = 0; r < 4; ++r) {
            const int c = mt * 16 + g * 4 + r;
            out[obase + (size_t)r * HWN] = xr[r] + gm * (D[r] + bo[c]);
        }
    }
}

extern "C" void kernel_launch(void* const* d_in, const int* in_sizes, int n_in,
                              void* d_out, int out_size, void* d_ws, size_t ws_size,
                              hipStream_t stream) {
    const float* x     = (const float*)d_in[0];
    const float* Wq    = (const float*)d_in[1];
    const float* bq    = (const float*)d_in[2];
    const float* Wk    = (const float*)d_in[3];
    const float* bk    = (const float*)d_in[4];
    const float* Wv    = (const float*)d_in[5];
    const float* bv    = (const float*)d_in[6];
    const float* Wo    = (const float*)d_in[7];
    const float* bo    = (const float*)d_in[8];
    const float* gamma = (const float*)d_in[9];
    float* out = (float*)d_out;

    u16* Qp = (u16*)d_ws;                        // 8*4096*16 bf16 = 1 MB
    u16* Kp = Qp + (size_t)NB * HWN * AD;        // 8*1024*16 bf16 = 256 KB
    u16* Vt = Kp + (size_t)NB * PJ * AD;         // 8*64*1024 bf16 = 1 MB
    unsigned* flags = (unsigned*)((char*)d_ws + (3u << 20));   // 512 words @3MB

    void* args[] = {
        (void*)&x,  (void*)&Wq, (void*)&bq, (void*)&Wk, (void*)&bk,
        (void*)&Wv, (void*)&bv, (void*)&Wo, (void*)&bo, (void*)&gamma,
        (void*)&Qp, (void*)&Kp, (void*)&Vt, (void*)&flags, (void*)&out
    };
    hipError_t err = hipLaunchCooperativeKernel((const void*)k_fused, dim3(512),
                                                dim3(256), args, 0, stream);
    if (err != hipSuccess) {
        // deterministic fallback: proven round-8 split pair
        k_proj<<<dim3(32, NB, 2), 256, 0, stream>>>(x, Wq, bq, Wk, bk, Wv, bv,
                                                    Qp, Kp, Vt);
        k_attn<<<dim3(64, NB), 256, 0, stream>>>(x, Qp, Kp, Vt, Wo, bo, gamma, out);
    }
}

// Round 10
// 110.551 us; speedup vs baseline: 1.7014x; 1.7014x over previous
//
#include <hip/hip_runtime.h>
#include <hip/hip_bf16.h>
#include <cstddef>

#define CC   128
#define AD   16
#define VD   64
#define HWN  4096
#define PJ   1024
#define NB   8

typedef short short8 __attribute__((ext_vector_type(8)));
typedef float f32x4  __attribute__((ext_vector_type(4)));
typedef unsigned short u16;

__device__ inline u16 f2bf(float f) {
    __hip_bfloat16 h = __float2bfloat16(f);
    union { __hip_bfloat16 h; u16 u; } c; c.h = h; return c.u;
}
__device__ inline unsigned pk2(float a, float b) {
    __hip_bfloat162 h = __float22bfloat162_rn(make_float2(a, b));
    union { __hip_bfloat162 h; unsigned u; } c; c.h = h; return c.u;
}

// XOR-swizzled physical element index for bf16 LDS tiles (8-elem blocks):
// conflict-free ds_read_b128 MFMA fragment reads.
__device__ inline int ph128(int r, int c) { return r * 128 + ((((c >> 3) ^ (r & 7)) << 3) | (c & 7)); }
__device__ inline int ph64 (int r, int c) { return r * 64  + ((((c >> 3) ^ (r & 7)) << 3) | (c & 7)); }

__device__ inline void stage16(const u16* g, u16* l) {
#if __has_builtin(__builtin_amdgcn_global_load_lds)
    __builtin_amdgcn_global_load_lds(
        (const __attribute__((address_space(1))) unsigned int*)g,
        (__attribute__((address_space(3))) unsigned int*)l, 16, 0, 0);
#else
    *(uint4*)l = *(const uint4*)g;
#endif
}

// ---------------------------------------------------------------------------
// Kernel 1: QKV projection (MFMA, M=64 pos x K=128 ch x N=96) + 2x2 maxpool
// in registers.  UNCHANGED from round 8 (proven).
// Outputs bf16: Qp[n][4096][16], Kp[n][1024][16], Vt[n][64][1024].
// ---------------------------------------------------------------------------
__global__ __launch_bounds__(256, 4) void k_proj(
    const float* __restrict__ x,
    const float* __restrict__ Wq, const float* __restrict__ bq,
    const float* __restrict__ Wk, const float* __restrict__ bk,
    const float* __restrict__ Wv, const float* __restrict__ bv,
    u16* __restrict__ Qp, u16* __restrict__ Kp, u16* __restrict__ Vt)
{
    __shared__ __align__(16) u16 xT[64 * 128];
    __shared__ __align__(16) u16 WT[96 * 128];

    const int tile = blockIdx.x, n = blockIdx.y, z = blockIdx.z, t = threadIdx.x;
    const int l = t & 63, w = t >> 6, g = l >> 4, lm = l & 15;
    const int p0 = tile * 128;

    {
        const float* xb = x + (size_t)n * CC * HWN + p0 + z * 32;
#pragma unroll
        for (int it = 0; it < 2; ++it) {
            const int idx = t + 256 * it;
            const int p4 = idx & 15, c4 = idx >> 4;
            const int gofs = (p4 & 7) * 4 + (p4 >> 3) * 64;
            const float* bp = xb + gofs;
            const f32x4 r0 = *(const f32x4*)(bp + (size_t)(c4 * 4 + 0) * HWN);
            const f32x4 r1 = *(const f32x4*)(bp + (size_t)(c4 * 4 + 1) * HWN);
            const f32x4 r2 = *(const f32x4*)(bp + (size_t)(c4 * 4 + 2) * HWN);
            const f32x4 r3 = *(const f32x4*)(bp + (size_t)(c4 * 4 + 3) * HWN);
#pragma unroll
            for (int pp = 0; pp < 4; ++pp) {
                const int lp = p4 * 4 + pp;
                uint2 v;
                v.x = pk2(r0[pp], r1[pp]);
                v.y = pk2(r2[pp], r3[pp]);
                *(uint2*)&xT[lp * 128 + ((((c4 >> 1) ^ (lp & 7)) << 3) | ((c4 & 1) * 4))] = v;
            }
        }
    }
#pragma unroll
    for (int it = 0; it < 2; ++it) {
        const int idx = t + 256 * it;
        const int d4 = idx & 3, ch = idx >> 2;
        float4 v = *(const float4*)(Wq + ch * AD + d4 * 4);
        WT[ph128(d4 * 4 + 0, ch)] = f2bf(v.x);
        WT[ph128(d4 * 4 + 1, ch)] = f2bf(v.y);
        WT[ph128(d4 * 4 + 2, ch)] = f2bf(v.z);
        WT[ph128(d4 * 4 + 3, ch)] = f2bf(v.w);
        v = *(const float4*)(Wk + ch * AD + d4 * 4);
        WT[ph128(16 + d4 * 4 + 0, ch)] = f2bf(v.x);
        WT[ph128(16 + d4 * 4 + 1, ch)] = f2bf(v.y);
        WT[ph128(16 + d4 * 4 + 2, ch)] = f2bf(v.z);
        WT[ph128(16 + d4 * 4 + 3, ch)] = f2bf(v.w);
    }
#pragma unroll
    for (int it = 0; it < 8; ++it) {
        const int idx = t + 256 * it;
        const int d4 = idx & 15, ch = idx >> 4;
        const float4 v = *(const float4*)(Wv + ch * VD + d4 * 4);
        WT[ph128(32 + d4 * 4 + 0, ch)] = f2bf(v.x);
        WT[ph128(32 + d4 * 4 + 1, ch)] = f2bf(v.y);
        WT[ph128(32 + d4 * 4 + 2, ch)] = f2bf(v.z);
        WT[ph128(32 + d4 * 4 + 3, ch)] = f2bf(v.w);
    }
    __syncthreads();

    const int pw = w & 1, ng = w >> 1;
    f32x4 acc[2][3];
#pragma unroll
    for (int i = 0; i < 2; ++i)
#pragma unroll
        for (int j = 0; j < 3; ++j) acc[i][j] = (f32x4){0.f, 0.f, 0.f, 0.f};
#pragma unroll
    for (int ks = 0; ks < 4; ++ks) {
        const short8 a0 = *(const short8*)&xT[ph128(pw * 16 + lm,      ks * 32 + g * 8)];
        const short8 a1 = *(const short8*)&xT[ph128(32 + pw * 16 + lm, ks * 32 + g * 8)];
#pragma unroll
        for (int j = 0; j < 3; ++j) {
            const short8 b = *(const short8*)&WT[ph128((ng * 3 + j) * 16 + lm, ks * 32 + g * 8)];
            acc[0][j] = __builtin_amdgcn_mfma_f32_16x16x32_bf16(a0, b, acc[0][j], 0, 0, 0);
            acc[1][j] = __builtin_amdgcn_mfma_f32_16x16x32_bf16(a1, b, acc[1][j], 0, 0, 0);
        }
    }

    const int pbase = p0 + z * 32 + pw * 16 + g * 4;
    const int jp = tile * 32 + z * 16 + pw * 8 + g * 2;

    if (ng == 0) {
        const float bqv = bq[lm];
#pragma unroll
        for (int mi = 0; mi < 2; ++mi)
#pragma unroll
            for (int r = 0; r < 4; ++r)
                Qp[((size_t)n * HWN + pbase + mi * 64 + r) * AD + lm] = f2bf(acc[mi][0][r] + bqv);
        const float bkv = bk[lm];
#pragma unroll
        for (int a = 0; a < 2; ++a) {
            const float mx = fmaxf(fmaxf(acc[0][1][2 * a], acc[0][1][2 * a + 1]),
                                   fmaxf(acc[1][1][2 * a], acc[1][1][2 * a + 1])) + bkv;
            Kp[((size_t)n * PJ + jp + a) * AD + lm] = f2bf(mx);
        }
        {
            const float bvv = bv[lm];
            const float m0 = fmaxf(fmaxf(acc[0][2][0], acc[0][2][1]),
                                   fmaxf(acc[1][2][0], acc[1][2][1])) + bvv;
            const float m1 = fmaxf(fmaxf(acc[0][2][2], acc[0][2][3]),
                                   fmaxf(acc[1][2][2], acc[1][2][3])) + bvv;
            *(unsigned*)&Vt[((size_t)n * VD + lm) * PJ + jp] = pk2(m0, m1);
        }
    } else {
#pragma unroll
        for (int j = 0; j < 3; ++j) {
            const int dv = (j + 1) * 16 + lm;
            const float bvv = bv[dv];
            const float m0 = fmaxf(fmaxf(acc[0][j][0], acc[0][j][1]),
                                   fmaxf(acc[1][j][0], acc[1][j][1])) + bvv;
            const float m1 = fmaxf(fmaxf(acc[0][j][2], acc[0][j][3]),
                                   fmaxf(acc[1][j][2], acc[1][j][3])) + bvv;
            *(unsigned*)&Vt[((size_t)n * VD + dv) * PJ + jp] = pk2(m0, m1);
        }
    }
}

// ---------------------------------------------------------------------------
// Kernel 2: flash attention + out-proj + residual, all MFMA.
// ROUND-10 CHANGE: in-block split-j for 2x TLP.  Block = 512 thr (8 waves);
// wave w: q-tile wq=w&3 (16 q), j-half h=w>>2 (512 j as 4 chunks of 128).
// Grid (64,8) -> 512 blocks, 72.5 KB LDS -> 2 blocks/CU -> 4 waves/SIMD
// (was 2).  Per-wave critical path halves (4 chunks not 8); epilogue split
// across halves (4 c-tiles each).  Exact online-softmax merge of the two
// (m,l,O) states through LDS.
// ---------------------------------------------------------------------------
__global__ __launch_bounds__(512, 4) void k_attn(
    const float* __restrict__ x,
    const u16* __restrict__ Qp, const u16* __restrict__ Kp, const u16* __restrict__ Vt,
    const float* __restrict__ Wo, const float* __restrict__ bo,
    const float* __restrict__ gma,
    float* __restrict__ out)
{
    __shared__ __align__(16) u16 KV[2][10240];   // per j-half: K 2048 | V 8192
    __shared__ __align__(16) u16 PB[8 * 2048];   // per-wave P; reused: O1(f32)/O^T
    __shared__ float ml[4][16][2];               // h=1 (m, l) per q-tile

    const int n = blockIdx.y, t = threadIdx.x;
    const int q0b = blockIdx.x * 64;
    const int l = t & 63, w = t >> 6, g = l >> 4, lm = l & 15;
    const int wq = w & 3, h = w >> 2;            // q-tile, j-half
    const int th = t & 255;                      // thread index within half

    // Q fragment for q-tile wq (g>=2 lanes are the K=16..31 zero pad)
    short8 qf = {0, 0, 0, 0, 0, 0, 0, 0};
    if (g < 2)
        qf = *(const short8*)(Qp + ((size_t)n * HWN + q0b + wq * 16 + lm) * AD + g * 8);

    // per-lane global source addresses (swizzle on global side)
    const u16* Kg = Kp + (size_t)n * PJ * AD
                  + (size_t)(th >> 1) * AD + ((th & 1) ^ ((th >> 1) & 1)) * 8;
    const u16* Vg0 = Vt + (size_t)n * VD * PJ;

    u16* Pl = PB + w * 2048;

    f32x4 O[4];
#pragma unroll
    for (int i = 0; i < 4; ++i) O[i] = (f32x4){0.f, 0.f, 0.f, 0.f};
    float mr = -1e30f, lr = 0.f;                 // per q = lm (replicated over g)

    for (int i = 0; i < 4; ++i) {
        const int j0 = (h * 4 + i) * 128;        // this half's chunk
        u16* Kb = KV[h];
        // ---- stage K chunk of this half (th covers 256 lanes x 16 B) ----
        stage16(Kg + (size_t)j0 * AD, &Kb[th * 8]);
        // ---- stage V chunk: wave (wq,h) covers dv = wq*16 + ii*4 + g ----
#pragma unroll
        for (int ii = 0; ii < 4; ++ii) {
            const int dv = wq * 16 + ii * 4 + g;
            stage16(Vg0 + (size_t)dv * PJ + j0 + (((l & 15) ^ (dv & 7)) * 8),
                    &Kb[2048 + (wq * 4 + ii) * 512 + l * 8]);
        }
        __syncthreads();

        const u16* Kl = KV[h];
        const u16* Vl = KV[h] + 2048;

        // ---- scores^T: St[row=j-in-tile=4g+r][col=q=lm] ----
        f32x4 St[8];
#pragma unroll
        for (int jt = 0; jt < 8; ++jt) {
            short8 kb = {0, 0, 0, 0, 0, 0, 0, 0};
            if (g < 2) {
                const int j = jt * 16 + lm;
                kb = *(const short8*)&Kl[(j * 2 + (g ^ (j & 1))) * 8];
            }
            const f32x4 z4 = (f32x4){0.f, 0.f, 0.f, 0.f};
            St[jt] = __builtin_amdgcn_mfma_f32_16x16x32_bf16(kb, qf, z4, 0, 0, 0);
        }

        // ---- online softmax: register tree + 2 shfl_xor ----
        float cm = St[0][0];
#pragma unroll
        for (int jt = 0; jt < 8; ++jt)
#pragma unroll
            for (int r = 0; r < 4; ++r) cm = fmaxf(cm, St[jt][r]);
        cm = fmaxf(cm, __shfl_xor(cm, 16));
        cm = fmaxf(cm, __shfl_xor(cm, 32));
        const float nm = fmaxf(mr, cm);
        const float al = __expf(mr - nm);
        mr = nm;
        float sum = 0.f;
#pragma unroll
        for (int jt = 0; jt < 8; ++jt)
#pragma unroll
            for (int r = 0; r < 4; ++r) {
                const float p = __expf(St[jt][r] - nm);
                St[jt][r] = p;
                sum += p;
            }
        sum += __shfl_xor(sum, 16);
        sum += __shfl_xor(sum, 32);
        lr = lr * al + sum;

#pragma unroll
        for (int r = 0; r < 4; ++r) {
            const float ar = __shfl(al, g * 4 + r);
            O[0][r] *= ar; O[1][r] *= ar; O[2][r] *= ar; O[3][r] *= ar;
        }

        // ---- P pack + b64 write ----
#pragma unroll
        for (int jt = 0; jt < 8; ++jt) {
            uint2 dw;
            dw.x = pk2(St[jt][0], St[jt][1]);
            dw.y = pk2(St[jt][2], St[jt][3]);
            *(uint2*)&Pl[lm * 128 + (((2 * jt + (g >> 1)) ^ (lm & 7)) << 3) + 4 * (g & 1)] = dw;
        }

        // ---- P @ V ----
#pragma unroll
        for (int ks = 0; ks < 4; ++ks) {
            const short8 pf = *(const short8*)&Pl[ph128(lm, ks * 32 + g * 8)];
#pragma unroll
            for (int dt = 0; dt < 4; ++dt) {
                const short8 vf = *(const short8*)&Vl[ph128(dt * 16 + lm, ks * 32 + g * 8)];
                O[dt] = __builtin_amdgcn_mfma_f32_16x16x32_bf16(pf, vf, O[dt], 0, 0, 0);
            }
        }
        __syncthreads();   // slot free for next chunk
    }

    // ---- merge halves: h=1 publishes raw (O, m, l); h=0 combines ----
    if (h == 1) {
        float* OF = (float*)(PB + w * 2048);     // own P region as f32 [16q][64dv]
#pragma unroll
        for (int r = 0; r < 4; ++r)
#pragma unroll
            for (int dt = 0; dt < 4; ++dt)
                OF[(g * 4 + r) * 64 + dt * 16 + lm] = O[dt][r];
        if (l < 16) { ml[wq][lm][0] = mr; ml[wq][lm][1] = lr; }
    }
    __syncthreads();

    u16* Ol = PB + wq * 2048;                    // merged O^T (bf16, ph64)
    if (h == 0) {
        const float* OF = (const float*)(PB + (wq + 4) * 2048);
        const float m1 = ml[wq][lm][0], l1 = ml[wq][lm][1];
        const float mf = fmaxf(mr, m1);
        const float a0 = __expf(mr - mf), a1 = __expf(m1 - mf);
        const float inv = 1.f / (lr * a0 + l1 * a1);
#pragma unroll
        for (int r = 0; r < 4; ++r) {
            const int row = g * 4 + r;
            const float ar0 = __shfl(a0, row), ar1 = __shfl(a1, row);
            const float ivr = __shfl(inv, row);
#pragma unroll
            for (int dt = 0; dt < 4; ++dt)
                Ol[ph64(row, dt * 16 + lm)] =
                    f2bf((O[dt][r] * ar0 + OF[row * 64 + dt * 16 + lm] * ar1) * ivr);
        }
    }
    // ---- stage WoT[c][dv] into KV region (dead) — all 512 threads ----
    u16* WoTl = (u16*)KV;
#pragma unroll
    for (int it = 0; it < 4; ++it) {
        const int idx = t + 512 * it;            // 0..2047
        const int c4 = idx & 31, dv = idx >> 5;
        const float4 v = *(const float4*)(Wo + dv * CC + c4 * 4);
        WoTl[ph64(c4 * 4 + 0, dv)] = f2bf(v.x);
        WoTl[ph64(c4 * 4 + 1, dv)] = f2bf(v.y);
        WoTl[ph64(c4 * 4 + 2, dv)] = f2bf(v.z);
        WoTl[ph64(c4 * 4 + 3, dv)] = f2bf(v.w);
    }
    __syncthreads();

    // ---- out-proj: wave (wq,h) does c-tiles mt = h*4..h*4+3 for q-tile wq ----
    const float gm = gma[0];
#pragma unroll
    for (int j = 0; j < 4; ++j) {
        const int mt = h * 4 + j;
        float xr[4];
        const size_t obase = ((size_t)n * CC + mt * 16 + g * 4) * HWN + q0b + wq * 16 + lm;
#pragma unroll
        for (int r = 0; r < 4; ++r) xr[r] = x[obase + (size_t)r * HWN];
        f32x4 D = (f32x4){0.f, 0.f, 0.f, 0.f};
#pragma unroll
        for (int ks = 0; ks < 2; ++ks) {
            const short8 af = *(const short8*)&WoTl[ph64(mt * 16 + lm, ks * 32 + g * 8)];
            const short8 bf = *(const short8*)&Ol[ph64(lm, ks * 32 + g * 8)];
            D = __builtin_amdgcn_mfma_f32_16x16x32_bf16(af, bf, D, 0, 0, 0);
        }
#pragma unroll
        for (int r = 0; r < 4; ++r) {
            const int c = mt * 16 + g * 4 + r;
            out[obase + (size_t)r * HWN] = xr[r] + gm * (D[r] + bo[c]);
        }
    }
}

extern "C" void kernel_launch(void* const* d_in, const int* in_sizes, int n_in,
                              void* d_out, int out_size, void* d_ws, size_t ws_size,
                              hipStream_t stream) {
    const float* x     = (const float*)d_in[0];
    const float* Wq    = (const float*)d_in[1];
    const float* bq    = (const float*)d_in[2];
    const float* Wk    = (const float*)d_in[3];
    const float* bk    = (const float*)d_in[4];
    const float* Wv    = (const float*)d_in[5];
    const float* bv    = (const float*)d_in[6];
    const float* Wo    = (const float*)d_in[7];
    const float* bo    = (const float*)d_in[8];
    const float* gamma = (const float*)d_in[9];
    float* out = (float*)d_out;

    u16* Qp = (u16*)d_ws;                        // 8*4096*16 bf16 = 1 MB
    u16* Kp = Qp + (size_t)NB * HWN * AD;        // 8*1024*16 bf16 = 256 KB
    u16* Vt = Kp + (size_t)NB * PJ * AD;         // 8*64*1024 bf16 = 1 MB

    k_proj<<<dim3(32, NB, 2), 256, 0, stream>>>(x, Wq, bq, Wk, bk, Wv, bv, Qp, Kp, Vt);
    k_attn<<<dim3(64, NB), 512, 0, stream>>>(x, Qp, Kp, Vt, Wo, bo, gamma, out);
}